// Round 11
// baseline (164.257 us; speedup 1.0000x reference)
//
#include <hip/hip_runtime.h>

#define PPn 8192
#define KKn 20
#define KPn (PPn*KKn)
constexpr float EPS_ = 1e-5f;

typedef __attribute__((ext_vector_type(8))) short s8v;
typedef __attribute__((ext_vector_type(4))) float f32x4;
#define MFMA16 __builtin_amdgcn_mfma_f32_16x16x32_bf16

// ---- ws layout (float offsets) ----
constexpr size_t OFF_F0    = 0;        // 8192*64
constexpr size_t OFF_IDX   = 524288;   // 8192*20 int
constexpr size_t OFF_XYZ   = 688128;   // 8192*20*6
constexpr size_t OFF_HM    = 1671168;  // 160*42
constexpr size_t OFF_PM    = 1677888;  // 4*12 pad 64
constexpr size_t OFF_SCOEF = 1677952;  // 3*32 pad 128
constexpr size_t OFF_PCOEF = 1678080;  // 3*128
constexpr size_t OFF_BN4C  = 1678464;  // 256
constexpr size_t OFF_W2    = 1678848;  // 8192*1024 bf16 = 4194304 f -> 5873152
constexpr size_t OFF_A2    = 5873152;  // 8192*64 (a3 aliases) -> 6397440
constexpr size_t OFF_A4    = 6397440;  // 8192*128 -> 7446016
constexpr size_t OFF_A4P   = 7446016;  // 8192*256 bf16 = 1048576 f -> 8494592
constexpr size_t OFF_P2    = 8494592;  // 256*64*2 -> 8527360
constexpr size_t OFF_P3    = 8527360;  // -> 8560128
constexpr size_t OFF_P4    = 8560128;  // 256*128*2 -> 8625664
constexpr size_t OFF_P5    = 8625664;  // 128*1024*2 -> 8887808
constexpr size_t OFF_MX5   = 8887808;  // 128*1024 -> 9018880
constexpr size_t OFF_BT2   = 9018880;  // 64*1536 bf16 -> 9068032
constexpr size_t OFF_BT3   = 9068032;  // -> 9117184
constexpr size_t OFF_BT4   = 9117184;  // 128*1536 bf16 -> 9215488
constexpr size_t OFF_BT5   = 9215488;  // 1024*384 bf16 -> 9412096
constexpr size_t OFF_POOL  = 9412096;  // 8*1024 -> 9420288
constexpr size_t OFF_A6    = 9420288;  // 8*512 -> 9424384
constexpr size_t OFF_CP    = 9424384;  // 6*8192*128 = 6291456 -> 15715840 (62.9 MB total)

__device__ __forceinline__ float wredf(float v) {
  #pragma unroll
  for (int o = 32; o > 0; o >>= 1) v += __shfl_xor(v, o, 64);
  return v;
}
__device__ __forceinline__ int wmini(int v) {
  #pragma unroll
  for (int o = 32; o > 0; o >>= 1) v = min(v, __shfl_xor(v, o, 64));
  return v;
}
__device__ __forceinline__ unsigned short f2bf(float f) {   // RNE
  unsigned int u = __float_as_uint(f);
  return (unsigned short)((u + 0x7FFFu + ((u >> 16) & 1u)) >> 16);
}
__device__ __forceinline__ float bf2f(unsigned short h) {
  return __uint_as_float(((unsigned int)h) << 16);
}

// ---------------- KNN + xyz + f0 (blocks 0..2047) | B-split (2048..5119) ----------------
__global__ __launch_bounds__(256) void k_prep(const float* __restrict__ x,
    const float* __restrict__ c1w, int* __restrict__ idxg,
    float* __restrict__ xyz, float* __restrict__ f0,
    const float* __restrict__ mat2, const float* __restrict__ mat3,
    const float* __restrict__ mat4, const float* __restrict__ c5w,
    unsigned short* __restrict__ bt2, unsigned short* __restrict__ bt3,
    unsigned short* __restrict__ bt4, unsigned short* __restrict__ bt5)
{
  int tid = threadIdx.x;
  if (blockIdx.x >= 2048) {           // ---- b-split part ----
    int blk = blockIdx.x - 2048;
    if (blk < 384) {                  // Bt2: 64 x 1536
      int e = blk*256 + tid;
      int o = e / 1536, k2 = e % 1536, p = k2 >> 9, k = k2 & 511;
      float f = mat2[(k & 63)*512 + (k >> 6)*64 + o];
      unsigned short h = f2bf(f);
      bt2[e] = (p < 2) ? h : f2bf(f - bf2f(h));
    } else if (blk < 768) {
      int e = (blk - 384)*256 + tid;
      int o = e / 1536, k2 = e % 1536, p = k2 >> 9, k = k2 & 511;
      float f = mat3[(k & 63)*512 + (k >> 6)*64 + o];
      unsigned short h = f2bf(f);
      bt3[e] = (p < 2) ? h : f2bf(f - bf2f(h));
    } else if (blk < 1536) {          // Bt4: 128 x 1536
      int e = (blk - 768)*256 + tid;
      int o = e / 1536, k2 = e % 1536, p = k2 >> 9, k = k2 & 511;
      float f = mat4[(k & 63)*1024 + (k >> 6)*128 + o];
      unsigned short h = f2bf(f);
      bt4[e] = (p < 2) ? h : f2bf(f - bf2f(h));
    } else {                          // Bt5: 1024 x 384
      int e = (blk - 1536)*256 + tid;
      int o = e / 384, k2 = e % 384, p = k2 >> 7, k = k2 & 127;
      float f = c5w[o*128 + k];
      unsigned short h = f2bf(f);
      bt5[e] = (p < 2) ? h : f2bf(f - bf2f(h));
    }
    return;
  }
  __shared__ float4 pts4[1024];
  int b = blockIdx.x >> 8;
  int wid = tid >> 6, lane = tid & 63;
  for (int i = tid; i < 1024; i += 256) {
    float px = x[(b*3+0)*1024 + i];
    float py = x[(b*3+1)*1024 + i];
    float pz = x[(b*3+2)*1024 + i];
    pts4[i] = make_float4(px, py, pz, px*px + py*py + pz*pz);
  }
  __syncthreads();
  int nq = ((blockIdx.x & 255) << 2) + wid;
  float4 q = pts4[nq];
  int qrow = b*1024 + nq;
  {
    float w0 = c1w[lane*3+0], w1 = c1w[lane*3+1], w2 = c1w[lane*3+2];
    f0[(size_t)qrow*64 + lane] = q.x*w0 + q.y*w1 + q.z*w2;
  }
  unsigned int uk[16];
  #pragma unroll
  for (int i = 0; i < 16; ++i) {
    float4 pm = pts4[i*64 + lane];
    float d = 2.f*(q.x*pm.x + q.y*pm.y + q.z*pm.z) - q.w - pm.w;
    unsigned int bits = __float_as_uint(d);
    uk[i] = bits ^ ((bits & 0x80000000u) ? 0xFFFFFFFFu : 0x80000000u);
  }
  unsigned int lo = 0u, hi = 0xFFFFFFFFu;
  while (lo < hi) {
    unsigned int mid = lo + ((hi - lo) >> 1);
    int cnt = 0;
    #pragma unroll
    for (int i = 0; i < 16; ++i) cnt += (int)__popcll(__ballot(uk[i] > mid));
    if (cnt <= 19) hi = mid; else lo = mid + 1u;
  }
  unsigned int V = lo;
  unsigned int sel = 0; int cg = 0;
  #pragma unroll
  for (int i = 0; i < 16; ++i) {
    bool gt = uk[i] > V;
    if (gt) sel |= (1u << i);
    cg += (int)__popcll(__ballot(gt));
  }
  int r = 20 - cg;            // #ties to take, smallest index first
  unsigned int taken = 0;
  while (r > 0) {
    int jm = 0x7FFFFFFF;
    #pragma unroll
    for (int i = 0; i < 16; ++i)
      if ((uk[i] == V) && !((taken >> i) & 1u) && jm == 0x7FFFFFFF) jm = i*64 + lane;
    int jw = wmini(jm);
    if ((jw & 63) == lane) { int ii = jw >> 6; taken |= (1u << ii); sel |= (1u << ii); }
    --r;
  }
  int cl = __popc(sel);
  int pre = cl;
  #pragma unroll
  for (int o = 1; o < 64; o <<= 1) { int t = __shfl_up(pre, o, 64); if (lane >= o) pre += t; }
  int slot = pre - cl;
  #pragma unroll
  for (int i = 0; i < 16; ++i) {
    if ((sel >> i) & 1u) {
      int j = i*64 + lane;
      idxg[qrow*20 + slot] = b*1024 + j;
      float4 pm = pts4[j];
      float* xr = xyz + (size_t)(qrow*20 + slot)*6;
      xr[0] = pm.x - q.x; xr[1] = pm.y - q.y; xr[2] = pm.z - q.z;
      xr[3] = pm.x; xr[4] = pm.y; xr[5] = pm.z;
      ++slot;
    }
  }
}

// ---------------- stats: xyz moments (0..159) + pts moments (160..163), fence-free ----------------
__global__ __launch_bounds__(256) void k_stats(const float* __restrict__ xyz,
    const float* __restrict__ x, float* __restrict__ hMom, float* __restrict__ pM)
{
  __shared__ float lred[512];
  int tid = threadIdx.x, blk = blockIdx.x;
  int wid = tid >> 6, lane = tid & 63;
  if (blk < 160) {
    float m1[6] = {0,0,0,0,0,0};
    float m2[36];
    #pragma unroll
    for (int i = 0; i < 36; ++i) m2[i] = 0.f;
    for (int it = 0; it < 4; ++it) {
      size_t rr = (size_t)blk*1024 + it*256 + tid;
      const float* xr = xyz + rr*6;
      float v[6];
      #pragma unroll
      for (int d = 0; d < 6; ++d) v[d] = xr[d];
      #pragma unroll
      for (int d = 0; d < 6; ++d) {
        m1[d] += v[d];
        #pragma unroll
        for (int e = 0; e < 6; ++e) m2[d*6+e] += v[d]*v[e];
      }
    }
    #pragma unroll
    for (int i = 0; i < 6; ++i) m1[i] = wredf(m1[i]);
    #pragma unroll
    for (int i = 0; i < 36; ++i) m2[i] = wredf(m2[i]);
    if (lane == 0) {
      #pragma unroll
      for (int i = 0; i < 6; ++i) lred[wid*42 + i] = m1[i];
      #pragma unroll
      for (int i = 0; i < 36; ++i) lred[wid*42 + 6 + i] = m2[i];
    }
    __syncthreads();
    if (tid < 42) hMom[blk*42 + tid] = lred[tid] + lred[42+tid] + lred[84+tid] + lred[126+tid];
  } else {
    int pb = blk - 160;           // 2 batches per block
    float m1[3] = {0,0,0};
    float m2[9] = {0,0,0,0,0,0,0,0,0};
    for (int b2 = 0; b2 < 2; ++b2) {
      int b = pb*2 + b2;
      for (int it = 0; it < 4; ++it) {
        int i = it*256 + tid;
        float p0 = x[(b*3+0)*1024 + i];
        float p1 = x[(b*3+1)*1024 + i];
        float p2 = x[(b*3+2)*1024 + i];
        m1[0]+=p0; m1[1]+=p1; m1[2]+=p2;
        m2[0]+=p0*p0; m2[1]+=p0*p1; m2[2]+=p0*p2;
        m2[3]+=p1*p0; m2[4]+=p1*p1; m2[5]+=p1*p2;
        m2[6]+=p2*p0; m2[7]+=p2*p1; m2[8]+=p2*p2;
      }
    }
    #pragma unroll
    for (int i = 0; i < 3; ++i) m1[i] = wredf(m1[i]);
    #pragma unroll
    for (int i = 0; i < 9; ++i) m2[i] = wredf(m2[i]);
    if (lane == 0) {
      #pragma unroll
      for (int i = 0; i < 3; ++i) lred[wid*12 + i] = m1[i];
      #pragma unroll
      for (int i = 0; i < 9; ++i) lred[wid*12 + 3 + i] = m2[i];
    }
    __syncthreads();
    if (tid < 12) pM[pb*12 + tid] = lred[tid] + lred[12+tid] + lred[24+tid] + lred[36+tid];
  }
}

// ---------------- coefA: moments -> scorenet coefs (3 stages) + bn1 coefs (1 block) ----------------
__global__ __launch_bounds__(256) void k_coefA(
    const float* __restrict__ hMom, const float* __restrict__ pM,
    const float* __restrict__ c1w, const float* __restrict__ bn1g, const float* __restrict__ bn1b,
    const float* __restrict__ w1a, const float* __restrict__ w1b, const float* __restrict__ w1c,
    const float* __restrict__ sga, const float* __restrict__ sgb, const float* __restrict__ sgc,
    const float* __restrict__ sba, const float* __restrict__ sbb, const float* __restrict__ sbc,
    float* __restrict__ scoef, float* __restrict__ pcoef)
{
  __shared__ float lred[192];
  __shared__ float momS[42], pmS[12];
  int tid = threadIdx.x;
  if (tid < 168) {
    int ch = tid % 42, seg = tid / 42;
    float s = 0.f;
    #pragma unroll 8
    for (int pb = seg*40; pb < seg*40 + 40; ++pb) s += hMom[pb*42 + ch];
    lred[seg*42 + ch] = s;
  } else if (tid >= 192 && tid < 204) {
    int i = tid - 192;
    pmS[i] = pM[i] + pM[12+i] + pM[24+i] + pM[36+i];
  }
  __syncthreads();
  if (tid < 42) momS[tid] = (lred[tid] + lred[42+tid] + lred[84+tid] + lred[126+tid]) / (float)KPn;
  __syncthreads();
  if (tid < 48) {
    int st = tid >> 4, c = tid & 15;
    const float* w1 = (st == 0) ? w1a : (st == 1) ? w1b : w1c;
    const float* sg = (st == 0) ? sga : (st == 1) ? sgb : sgc;
    const float* sb = (st == 0) ? sba : (st == 1) ? sbb : sbc;
    float wv[6];
    #pragma unroll
    for (int d = 0; d < 6; ++d) wv[d] = w1[c*6 + d];
    float mu = 0.f, E2 = 0.f;
    #pragma unroll
    for (int d = 0; d < 6; ++d) mu += wv[d]*momS[d];
    #pragma unroll
    for (int d = 0; d < 6; ++d) {
      float qd = 0.f;
      #pragma unroll
      for (int e = 0; e < 6; ++e) qd += momS[6 + d*6 + e]*wv[e];
      E2 += wv[d]*qd;
    }
    float var = E2 - mu*mu;
    float rst = rsqrtf(var + EPS_);
    float g = sg[c];
    scoef[st*32 + c] = g*rst;
    scoef[st*32 + 16 + c] = sb[c] - mu*g*rst;
  } else if (tid >= 64 && tid < 128) {
    int c = tid - 64;
    float wv0 = c1w[c*3+0], wv1 = c1w[c*3+1], wv2 = c1w[c*3+2];
    float mu = (wv0*pmS[0] + wv1*pmS[1] + wv2*pmS[2]) / 8192.f;
    float E2 = (wv0*(pmS[3]*wv0 + pmS[4]*wv1 + pmS[5]*wv2)
              + wv1*(pmS[6]*wv0 + pmS[7]*wv1 + pmS[8]*wv2)
              + wv2*(pmS[9]*wv0 + pmS[10]*wv1 + pmS[11]*wv2)) / 8192.f;
    float var = E2 - mu*mu;
    float rst = rsqrtf(var + EPS_);
    float g = bn1g[c];
    pcoef[c] = g*rst;
    pcoef[64 + c] = bn1b[c] - mu*g*rst;
  }
}

// ---------------- W-build: per-wave scorenet + gather ----------------
__global__ __launch_bounds__(256) void k_wbuild(
    const float* __restrict__ xyz, const int* __restrict__ idxg,
    const float* __restrict__ aprev, const float* __restrict__ scoef,
    const float* __restrict__ pcoef,
    const float* __restrict__ w1, const float* __restrict__ w2, const float* __restrict__ b2,
    unsigned short* __restrict__ Wo)
{
  __shared__ float scoreS[4][20][8];
  int tid = threadIdx.x;
  int wid = tid >> 6, lane = tid & 63;
  int p = blockIdx.x*4 + wid;
  if (lane < 20) {
    const float* xr = xyz + (size_t)(p*20 + lane)*6;
    float v0=xr[0],v1=xr[1],v2=xr[2],v3=xr[3],v4=xr[4],v5=xr[5];
    float hb[16];
    #pragma unroll
    for (int c = 0; c < 16; ++c) {
      float h = v0*w1[c*6+0]+v1*w1[c*6+1]+v2*w1[c*6+2]+v3*w1[c*6+3]+v4*w1[c*6+4]+v5*w1[c*6+5];
      hb[c] = fmaxf(0.f, h*scoef[c] + scoef[16+c]);
    }
    float lg[8]; float mx = -3.4e38f;
    #pragma unroll
    for (int m = 0; m < 8; ++m) {
      float s = b2[m];
      #pragma unroll
      for (int c = 0; c < 16; ++c) s += hb[c]*w2[m*16+c];
      lg[m] = s; mx = fmaxf(mx, s);
    }
    float den = 0.f;
    #pragma unroll
    for (int m = 0; m < 8; ++m) { lg[m] = expf(lg[m]-mx); den += lg[m]; }
    #pragma unroll
    for (int m = 0; m < 8; ++m) scoreS[wid][lane][m] = lg[m]/den;
  }
  __syncthreads();
  float ps = pcoef[lane], ph = pcoef[64 + lane];
  float acc[8];
  #pragma unroll
  for (int m = 0; m < 8; ++m) acc[m] = 0.f;
  const int* ip = idxg + p*20;
  #pragma unroll
  for (int k = 0; k < 20; ++k) {
    int j = ip[k];
    float v = aprev[(size_t)j*64 + lane];
    v = fmaxf(0.f, v*ps + ph);
    #pragma unroll
    for (int m = 0; m < 8; ++m) acc[m] += scoreS[wid][k][m]*v;
  }
  #pragma unroll
  for (int m = 0; m < 8; ++m) {
    float v = acc[m];
    unsigned short h = f2bf(v);
    unsigned short l = f2bf(v - bf2f(h));
    Wo[(size_t)p*1024 + m*64 + lane] = h;
    Wo[(size_t)p*1024 + 512 + m*64 + lane] = l;
  }
}

// ---------------- K-split MFMA gemm: partial 64x64 tile over 256 K'-cols (fence-free) ----------------
template<int CO>
__global__ __launch_bounds__(256) void k_mg(
    const unsigned short* __restrict__ A, const unsigned short* __restrict__ Bt,
    float* __restrict__ Cp)
{
  __shared__ __align__(16) unsigned short As[4096];
  __shared__ __align__(16) unsigned short Bs[4096];
  int tid = threadIdx.x;
  int rb = blockIdx.x, gy = blockIdx.y, ck = blockIdx.z;
  int w = tid >> 6, lane = tid & 63;
  int wr = w & 1, wc = w >> 1;
  int r = tid >> 2, q = tid & 3;
  int abase = ((ck >> 1) == 1 ? 512 : 0) + (ck & 1)*256;
  int bbase = ck*256;
  f32x4 acc00 = {0,0,0,0}, acc01 = {0,0,0,0}, acc10 = {0,0,0,0}, acc11 = {0,0,0,0};
  const size_t arow = (size_t)(rb*64 + r)*1024 + abase + q*16;
  const size_t brow = (size_t)(gy*64 + r)*1536 + bbase + q*16;
  float4 ra0, ra1, rbv0, rbv1;
  #define MG_LOAD(IT) { \
    const float4* ap_ = (const float4*)(A + arow + (IT)*64); ra0 = ap_[0]; ra1 = ap_[1]; \
    const float4* bp_ = (const float4*)(Bt + brow + (IT)*64); rbv0 = bp_[0]; rbv1 = bp_[1]; }
  MG_LOAD(0);
  int wbase = r*128 + q*32, sw = (r & 7) << 4;
  for (int it = 0; it < 4; ++it) {
    __syncthreads();
    *(float4*)((char*)As + ((wbase)      ^ sw)) = ra0;
    *(float4*)((char*)As + ((wbase + 16) ^ sw)) = ra1;
    *(float4*)((char*)Bs + ((wbase)      ^ sw)) = rbv0;
    *(float4*)((char*)Bs + ((wbase + 16) ^ sw)) = rbv1;
    __syncthreads();
    if (it < 3) MG_LOAD(it + 1);
    #pragma unroll
    for (int ks = 0; ks < 2; ++ks) {
      int kb2 = (ks*32 + ((lane >> 4) << 3))*2;
      int ar0 = wr*32 + (lane & 15), ar1 = ar0 + 16;
      int bc0 = wc*32 + (lane & 15), bc1 = bc0 + 16;
      s8v a0 = *(const s8v*)((const char*)As + ((ar0*128 + kb2) ^ ((ar0 & 7) << 4)));
      s8v a1 = *(const s8v*)((const char*)As + ((ar1*128 + kb2) ^ ((ar1 & 7) << 4)));
      s8v b0 = *(const s8v*)((const char*)Bs + ((bc0*128 + kb2) ^ ((bc0 & 7) << 4)));
      s8v b1 = *(const s8v*)((const char*)Bs + ((bc1*128 + kb2) ^ ((bc1 & 7) << 4)));
      acc00 = MFMA16(a0, b0, acc00, 0, 0, 0);
      acc01 = MFMA16(a0, b1, acc01, 0, 0, 0);
      acc10 = MFMA16(a1, b0, acc10, 0, 0, 0);
      acc11 = MFMA16(a1, b1, acc11, 0, 0, 0);
    }
  }
  #undef MG_LOAD
  int rr = (lane >> 4)*4, cc = lane & 15;
  float* Co = Cp + (size_t)ck*((size_t)8192*CO);
  size_t rbase = (size_t)rb*64 + wr*32 + rr;
  int cbase = gy*64 + wc*32 + cc;
  #pragma unroll
  for (int u = 0; u < 4; ++u) {
    Co[(rbase + u)*CO + cbase]           = acc00[u];
    Co[(rbase + u)*CO + cbase + 16]      = acc01[u];
    Co[(rbase + 16 + u)*CO + cbase]      = acc10[u];
    Co[(rbase + 16 + u)*CO + cbase + 16] = acc11[u];
  }
}

// ---------------- reduce 6 partials -> C + col partials (fence-free, 256 blocks x 32 rows) ----------------
template<int CO, int NCH>
__global__ __launch_bounds__(256) void k_red(
    const float* __restrict__ Cp, float* __restrict__ C, float* __restrict__ P)
{
  static_assert(NCH == 6, "hardwired 6-chunk sum");
  __shared__ float red[256][8];
  constexpr int F = (32*CO)/1024;          // 2 (CO=64) or 4 (CO=128)
  constexpr size_t SZ = (size_t)8192*CO;
  int tid = threadIdx.x, bid = blockIdx.x;  // 256 blocks, 32 rows each
  float cs[4] = {0,0,0,0}, cq[4] = {0,0,0,0};
  #pragma unroll
  for (int f = 0; f < F; ++f) {
    size_t idx = (size_t)bid*(32*CO) + f*1024 + tid*4;
    float4 u0 = *(const float4*)(Cp + idx);
    float4 u1 = *(const float4*)(Cp + SZ + idx);
    float4 u2 = *(const float4*)(Cp + 2*SZ + idx);
    float4 u3 = *(const float4*)(Cp + 3*SZ + idx);
    float4 u4 = *(const float4*)(Cp + 4*SZ + idx);
    float4 u5 = *(const float4*)(Cp + 5*SZ + idx);
    float4 v;
    v.x = ((u0.x + u1.x) + (u2.x + u3.x)) + (u4.x + u5.x);
    v.y = ((u0.y + u1.y) + (u2.y + u3.y)) + (u4.y + u5.y);
    v.z = ((u0.z + u1.z) + (u2.z + u3.z)) + (u4.z + u5.z);
    v.w = ((u0.w + u1.w) + (u2.w + u3.w)) + (u4.w + u5.w);
    *(float4*)(C + idx) = v;
    cs[0] += v.x; cq[0] += v.x*v.x;
    cs[1] += v.y; cq[1] += v.y*v.y;
    cs[2] += v.z; cq[2] += v.z*v.z;
    cs[3] += v.w; cq[3] += v.w*v.w;
  }
  #pragma unroll
  for (int u = 0; u < 4; ++u) { red[tid][2*u] = cs[u]; red[tid][2*u+1] = cq[u]; }
  __syncthreads();
  if (tid < CO) {
    int c = tid, base = c >> 2, slot = c & 3;
    float s = 0.f, qq = 0.f;
    #pragma unroll
    for (int j = 0; j < 256/(CO/4); ++j) {
      int t = base + (CO/4)*j;
      s += red[t][2*slot]; qq += red[t][2*slot+1];
    }
    P[((size_t)bid*CO + c)*2]     = s;
    P[((size_t)bid*CO + c)*2 + 1] = qq;
  }
}

// ---------------- coefB: P (256 rows) -> BN scale/shift (1 block) ----------------
template<int CO>
__global__ __launch_bounds__(256) void k_coefB(const float* __restrict__ P,
    const float* __restrict__ g, const float* __restrict__ b, float* __restrict__ coefOut)
{
  __shared__ float rs[256], rq[256];
  constexpr int NSEG = 256/CO;      // 4 (CO=64) or 2 (CO=128)
  constexpr int RPS  = 256/NSEG;    // 64 or 128
  int tid = threadIdx.x;
  int c = tid % CO, seg = tid / CO;
  float s = 0.f, qq = 0.f;
  #pragma unroll 8
  for (int j = 0; j < RPS; ++j) {
    int p2 = seg*RPS + j;
    s  += P[((size_t)p2*CO + c)*2];
    qq += P[((size_t)p2*CO + c)*2 + 1];
  }
  rs[seg*CO + c] = s; rq[seg*CO + c] = qq;
  __syncthreads();
  if (tid < CO) {
    float s2 = 0.f, q2 = 0.f;
    #pragma unroll
    for (int gs = 0; gs < NSEG; ++gs) { s2 += rs[gs*CO + tid]; q2 += rq[gs*CO + tid]; }
    float mu = s2/8192.f, var = q2/8192.f - mu*mu;
    float rst = rsqrtf(var + EPS_);
    coefOut[tid] = g[tid]*rst;
    coefOut[CO + tid] = b[tid] - mu*g[tid]*rst;
  }
}

// ---------------- pack: a4p = hi/lo bf16 of relu(bn4(a4)) ----------------
__global__ __launch_bounds__(256) void k_pack(const float* __restrict__ a4,
    const float* __restrict__ bnc, unsigned short* __restrict__ a4p)
{
  int gid = blockIdx.x*256 + threadIdx.x;   // 262144
  int row = gid >> 5, c4 = (gid & 31)*4;
  float4 v = *(const float4*)(a4 + (size_t)row*128 + c4);
  float y0 = fmaxf(0.f, v.x*bnc[c4+0] + bnc[128+c4+0]);
  float y1 = fmaxf(0.f, v.y*bnc[c4+1] + bnc[128+c4+1]);
  float y2 = fmaxf(0.f, v.z*bnc[c4+2] + bnc[128+c4+2]);
  float y3 = fmaxf(0.f, v.w*bnc[c4+3] + bnc[128+c4+3]);
  ushort4 hi = make_ushort4(f2bf(y0), f2bf(y1), f2bf(y2), f2bf(y3));
  ushort4 lov = make_ushort4(f2bf(y0 - bf2f(hi.x)), f2bf(y1 - bf2f(hi.y)),
                             f2bf(y2 - bf2f(hi.z)), f2bf(y3 - bf2f(hi.w)));
  *(ushort4*)(a4p + (size_t)row*256 + c4) = hi;
  *(ushort4*)(a4p + (size_t)row*256 + 128 + c4) = lov;
}

// ---------------- MFMA gemm5: a4p(bf16 hi/lo) x bt5 -> partials + max ----------------
__global__ __launch_bounds__(256) void k_g5(const unsigned short* __restrict__ A4P,
    const unsigned short* __restrict__ Bt,
    float* __restrict__ outPart, float* __restrict__ outMax)
{
  __shared__ __align__(16) unsigned short As[4096];
  __shared__ __align__(16) unsigned short Bs[4096];
  __shared__ float colS[4][64], colQ[4][64], colM[4][64];
  int tid = threadIdx.x;
  int rb = blockIdx.x, gy = blockIdx.y;
  int w = tid >> 6, lane = tid & 63;
  int wr = w & 1, wc = w >> 1;
  int r = tid >> 2, q = tid & 3;
  f32x4 acc00={0,0,0,0}, acc01={0,0,0,0}, acc10={0,0,0,0}, acc11={0,0,0,0};
  uint4 ua0, ua1, ub0, ub1;
  #define G5_LOAD(IT) { int p_ = (IT) >> 1; int acol = (p_ == 1 ? 128 : 0) + (((IT) & 1) << 6); \
    const uint4* ap_ = (const uint4*)(A4P + (size_t)(rb*64 + r)*256 + acol + q*16); \
    ua0 = ap_[0]; ua1 = ap_[1]; \
    const uint4* bp_ = (const uint4*)(Bt + (size_t)(gy*64 + r)*384 + (size_t)(IT)*64 + q*16); \
    ub0 = bp_[0]; ub1 = bp_[1]; }
  G5_LOAD(0);
  int wbase = r*128 + q*32, sw = (r & 7) << 4;
  for (int it = 0; it < 6; ++it) {
    __syncthreads();
    *(uint4*)((char*)As + ((wbase)      ^ sw)) = ua0;
    *(uint4*)((char*)As + ((wbase + 16) ^ sw)) = ua1;
    *(uint4*)((char*)Bs + ((wbase)      ^ sw)) = ub0;
    *(uint4*)((char*)Bs + ((wbase + 16) ^ sw)) = ub1;
    __syncthreads();
    if (it < 5) G5_LOAD(it + 1);
    #pragma unroll
    for (int ks = 0; ks < 2; ++ks) {
      int kb2 = (ks*32 + ((lane >> 4) << 3))*2;
      int ar0 = wr*32 + (lane & 15), ar1 = ar0 + 16;
      int bc0 = wc*32 + (lane & 15), bc1 = bc0 + 16;
      s8v a0 = *(const s8v*)((const char*)As + ((ar0*128 + kb2) ^ ((ar0 & 7) << 4)));
      s8v a1 = *(const s8v*)((const char*)As + ((ar1*128 + kb2) ^ ((ar1 & 7) << 4)));
      s8v b0 = *(const s8v*)((const char*)Bs + ((bc0*128 + kb2) ^ ((bc0 & 7) << 4)));
      s8v b1 = *(const s8v*)((const char*)Bs + ((bc1*128 + kb2) ^ ((bc1 & 7) << 4)));
      acc00 = MFMA16(a0, b0, acc00, 0, 0, 0);
      acc01 = MFMA16(a0, b1, acc01, 0, 0, 0);
      acc10 = MFMA16(a1, b0, acc10, 0, 0, 0);
      acc11 = MFMA16(a1, b1, acc11, 0, 0, 0);
    }
  }
  #undef G5_LOAD
  int cc = lane & 15;
  {
    float s0=0.f,q0=0.f,m0=-3.4e38f, s1=0.f,q1=0.f,m1=-3.4e38f;
    #pragma unroll
    for (int u = 0; u < 4; ++u) {
      s0 += acc00[u] + acc10[u]; q0 += acc00[u]*acc00[u] + acc10[u]*acc10[u];
      m0 = fmaxf(m0, fmaxf(acc00[u], acc10[u]));
      s1 += acc01[u] + acc11[u]; q1 += acc01[u]*acc01[u] + acc11[u]*acc11[u];
      m1 = fmaxf(m1, fmaxf(acc01[u], acc11[u]));
    }
    s0 += __shfl_xor(s0,16,64); s0 += __shfl_xor(s0,32,64);
    q0 += __shfl_xor(q0,16,64); q0 += __shfl_xor(q0,32,64);
    m0 = fmaxf(m0, __shfl_xor(m0,16,64)); m0 = fmaxf(m0, __shfl_xor(m0,32,64));
    s1 += __shfl_xor(s1,16,64); s1 += __shfl_xor(s1,32,64);
    q1 += __shfl_xor(q1,16,64); q1 += __shfl_xor(q1,32,64);
    m1 = fmaxf(m1, __shfl_xor(m1,16,64)); m1 = fmaxf(m1, __shfl_xor(m1,32,64));
    if (lane < 16) {
      colS[w][wc*32 + cc] = s0;      colQ[w][wc*32 + cc] = q0;      colM[w][wc*32 + cc] = m0;
      colS[w][wc*32 + 16 + cc] = s1; colQ[w][wc*32 + 16 + cc] = q1; colM[w][wc*32 + 16 + cc] = m1;
    }
  }
  __syncthreads();
  if (tid < 64) {
    int c = tid, wc2 = c >> 5;
    float s = colS[2*wc2][c] + colS[2*wc2+1][c];
    float qq = colQ[2*wc2][c] + colQ[2*wc2+1][c];
    float m = fmaxf(colM[2*wc2][c], colM[2*wc2+1][c]);
    outPart[((size_t)rb*1024 + gy*64 + c)*2]     = s;
    outPart[((size_t)rb*1024 + gy*64 + c)*2 + 1] = qq;
    outMax[(size_t)rb*1024 + gy*64 + c] = m;
  }
}

// ---------------- bn5 + relu + maxpool (128 blocks) ----------------
__global__ __launch_bounds__(256) void k_pool(const float* __restrict__ p5, const float* __restrict__ mx5,
    const float* __restrict__ g5, const float* __restrict__ b5, float* __restrict__ pool)
{
  __shared__ float red[4][64][2];
  int tid = threadIdx.x, bid = blockIdx.x;
  int b = bid >> 4, cg = bid & 15;
  int c4 = tid & 63, seg = tid >> 6;
  int ch = cg*64 + c4;
  float s = 0.f, qq = 0.f;
  for (int rb = seg*32; rb < seg*32 + 32; ++rb) {
    s  += p5[((size_t)rb*1024 + ch)*2];
    qq += p5[((size_t)rb*1024 + ch)*2 + 1];
  }
  red[seg][c4][0] = s; red[seg][c4][1] = qq;
  __syncthreads();
  if (seg == 0) {
    s  = red[0][c4][0] + red[1][c4][0] + red[2][c4][0] + red[3][c4][0];
    qq = red[0][c4][1] + red[1][c4][1] + red[2][c4][1] + red[3][c4][1];
    float mu = s / 8192.f;
    float var = qq / 8192.f - mu*mu;
    float rst = rsqrtf(var + EPS_);
    float mx = -3.4e38f;
    #pragma unroll
    for (int t = 0; t < 16; ++t) mx = fmaxf(mx, mx5[(size_t)(b*16 + t)*1024 + ch]);
    pool[b*1024 + ch] = fmaxf(0.f, g5[ch]*(mx - mu)*rst + b5[ch]);
  }
}

// ---------------- lin1: wave per output ----------------
__global__ __launch_bounds__(256) void k_lin1(const float* __restrict__ pool,
    const float* __restrict__ w, float* __restrict__ a6)
{
  int wid = threadIdx.x >> 6, lane = threadIdx.x & 63;
  int o = blockIdx.x*4 + wid;
  int r = o >> 9, c = o & 511;
  const float4* pr = (const float4*)(pool + r*1024);
  const float4* wr = (const float4*)(w + (size_t)c*1024);
  float s = 0.f;
  #pragma unroll
  for (int t = 0; t < 4; ++t) {
    float4 a = pr[lane + 64*t], b = wr[lane + 64*t];
    s += a.x*b.x + a.y*b.y + a.z*b.z + a.w*b.w;
  }
  s = wredf(s);
  if (lane == 0) a6[o] = s;
}

// ---------------- head: wave per output ----------------
__global__ __launch_bounds__(256) void k_head(const float* __restrict__ a6,
    const float* __restrict__ g6, const float* __restrict__ b6,
    const float* __restrict__ w2, const float* __restrict__ bb,
    float* __restrict__ out)
{
  int wid = threadIdx.x >> 6, lane = threadIdx.x & 63;
  int o = blockIdx.x*4 + wid;
  int r = o / 40, c2 = o % 40;
  float s = 0.f;
  #pragma unroll
  for (int j = 0; j < 8; ++j) {
    int c = lane + 64*j;
    float sum = 0.f, vr = 0.f;
    float v[8];
    #pragma unroll
    for (int rr = 0; rr < 8; ++rr) { v[rr] = a6[rr*512 + c]; sum += v[rr]; }
    #pragma unroll
    for (int rr = 0; rr < 8; ++rr) vr = (rr == r) ? v[rr] : vr;
    float mu = sum / 8.f;
    float qq = 0.f;
    #pragma unroll
    for (int rr = 0; rr < 8; ++rr) { float d = v[rr] - mu; qq += d*d; }
    float rst = rsqrtf(qq / 8.f + EPS_);
    float f6r = fmaxf(0.f, (vr - mu)*g6[c]*rst + b6[c]);
    s += f6r * w2[c2*512 + c];
  }
  s = wredf(s);
  if (lane == 0) out[o] = s + bb[c2];
}

extern "C" void kernel_launch(void* const* d_in, const int* in_sizes, int n_in,
                              void* d_out, int out_size, void* d_ws, size_t ws_size,
                              hipStream_t stream) {
  (void)in_sizes; (void)n_in; (void)out_size; (void)ws_size;
  const float* x     = (const float*)d_in[0];
  const float* c1w   = (const float*)d_in[1];
  const float* bn1g  = (const float*)d_in[2];
  const float* bn1b  = (const float*)d_in[3];
  const float* mat2  = (const float*)d_in[4];
  const float* mat3  = (const float*)d_in[5];
  const float* mat4  = (const float*)d_in[6];
  const float* sn2w1 = (const float*)d_in[7];
  const float* sn2g  = (const float*)d_in[8];
  const float* sn2b  = (const float*)d_in[9];
  const float* sn2w2 = (const float*)d_in[10];
  const float* sn2b2 = (const float*)d_in[11];
  const float* sn3w1 = (const float*)d_in[12];
  const float* sn3g  = (const float*)d_in[13];
  const float* sn3b  = (const float*)d_in[14];
  const float* sn3w2 = (const float*)d_in[15];
  const float* sn3b2 = (const float*)d_in[16];
  const float* sn4w1 = (const float*)d_in[17];
  const float* sn4g  = (const float*)d_in[18];
  const float* sn4b  = (const float*)d_in[19];
  const float* sn4w2 = (const float*)d_in[20];
  const float* sn4b2 = (const float*)d_in[21];
  const float* bn2g  = (const float*)d_in[22];
  const float* bn2b  = (const float*)d_in[23];
  const float* bn3g  = (const float*)d_in[24];
  const float* bn3b  = (const float*)d_in[25];
  const float* bn4g  = (const float*)d_in[26];
  const float* bn4b  = (const float*)d_in[27];
  const float* c5w   = (const float*)d_in[28];
  const float* bn5g  = (const float*)d_in[29];
  const float* bn5b  = (const float*)d_in[30];
  const float* l1w   = (const float*)d_in[31];
  const float* bn6g  = (const float*)d_in[32];
  const float* bn6b  = (const float*)d_in[33];
  const float* l2w   = (const float*)d_in[34];
  const float* l2b   = (const float*)d_in[35];
  float* ws   = (float*)d_ws;
  float* f0    = ws + OFF_F0;
  int*   idxg  = (int*)(ws + OFF_IDX);
  float* xyz   = ws + OFF_XYZ;
  float* hMom  = ws + OFF_HM;
  float* pM    = ws + OFF_PM;
  float* scoef = ws + OFF_SCOEF;
  float* pcoef = ws + OFF_PCOEF;
  float* bn4c  = ws + OFF_BN4C;
  unsigned short* W2  = (unsigned short*)(ws + OFF_W2);
  float* a2    = ws + OFF_A2;          // a3 aliases (lifetimes disjoint)
  float* a4    = ws + OFF_A4;
  unsigned short* a4p = (unsigned short*)(ws + OFF_A4P);
  float* p2    = ws + OFF_P2;
  float* p3    = ws + OFF_P3;
  float* p4    = ws + OFF_P4;
  float* p5    = ws + OFF_P5;
  float* mx5   = ws + OFF_MX5;
  unsigned short* bt2 = (unsigned short*)(ws + OFF_BT2);
  unsigned short* bt3 = (unsigned short*)(ws + OFF_BT3);
  unsigned short* bt4 = (unsigned short*)(ws + OFF_BT4);
  unsigned short* bt5 = (unsigned short*)(ws + OFF_BT5);
  float* pool  = ws + OFF_POOL;
  float* a6    = ws + OFF_A6;
  float* CP    = ws + OFF_CP;
  float* out   = (float*)d_out;

  k_prep<<<5120, 256, 0, stream>>>(x, c1w, idxg, xyz, f0,
      mat2, mat3, mat4, c5w, bt2, bt3, bt4, bt5);
  k_stats<<<164, 256, 0, stream>>>(xyz, x, hMom, pM);
  k_coefA<<<1, 256, 0, stream>>>(hMom, pM, c1w, bn1g, bn1b,
      sn2w1, sn3w1, sn4w1, sn2g, sn3g, sn4g, sn2b, sn3b, sn4b,
      scoef, pcoef);

  k_wbuild<<<2048, 256, 0, stream>>>(xyz, idxg, f0, scoef + 0, pcoef + 0,
      sn2w1, sn2w2, sn2b2, W2);
  k_mg<64><<<dim3(128, 1, 6), 256, 0, stream>>>(W2, bt2, CP);
  k_red<64, 6><<<256, 256, 0, stream>>>(CP, a2, p2);
  k_coefB<64><<<1, 256, 0, stream>>>(p2, bn2g, bn2b, pcoef + 128);

  k_wbuild<<<2048, 256, 0, stream>>>(xyz, idxg, a2, scoef + 32, pcoef + 128,
      sn3w1, sn3w2, sn3b2, W2);
  k_mg<64><<<dim3(128, 1, 6), 256, 0, stream>>>(W2, bt3, CP);
  k_red<64, 6><<<256, 256, 0, stream>>>(CP, a2 /*a3*/, p3);
  k_coefB<64><<<1, 256, 0, stream>>>(p3, bn3g, bn3b, pcoef + 256);

  k_wbuild<<<2048, 256, 0, stream>>>(xyz, idxg, a2 /*a3*/, scoef + 64, pcoef + 256,
      sn4w1, sn4w2, sn4b2, W2);
  k_mg<128><<<dim3(128, 2, 6), 256, 0, stream>>>(W2, bt4, CP);
  k_red<128, 6><<<256, 256, 0, stream>>>(CP, a4, p4);
  k_coefB<128><<<1, 256, 0, stream>>>(p4, bn4g, bn4b, bn4c);

  k_pack<<<1024, 256, 0, stream>>>(a4, bn4c, a4p);
  k_g5<<<dim3(128, 16), 256, 0, stream>>>(a4p, bt5, p5, mx5);

  k_pool<<<128, 256, 0, stream>>>(p5, mx5, bn5g, bn5b, pool);
  k_lin1<<<1024, 256, 0, stream>>>(pool, l1w, a6);
  k_head<<<80, 256, 0, stream>>>(a6, bn6g, bn6b, l2w, l2b, out);
}

// Round 12
// 159.037 us; speedup vs baseline: 1.0328x; 1.0328x over previous
//
#include <hip/hip_runtime.h>

#define PPn 8192
#define KKn 20
#define KPn (PPn*KKn)
constexpr float EPS_ = 1e-5f;

typedef __attribute__((ext_vector_type(8))) short s8v;
typedef __attribute__((ext_vector_type(4))) float f32x4;
#define MFMA16 __builtin_amdgcn_mfma_f32_16x16x32_bf16

// ---- ws layout (float offsets) ----
constexpr size_t OFF_F0    = 0;        // 8192*64
constexpr size_t OFF_IDX   = 524288;   // 8192*20 int
constexpr size_t OFF_XYZ   = 688128;   // 8192*20*6
constexpr size_t OFF_HM    = 1671168;  // 160*42
constexpr size_t OFF_PM    = 1677888;  // 4*12 pad 64
constexpr size_t OFF_SCOEF = 1677952;  // 3*32 pad 128
constexpr size_t OFF_PCOEF = 1678080;  // 3*128
constexpr size_t OFF_BN4C  = 1678464;  // 256
constexpr size_t OFF_W2    = 1678848;  // 8192*1024 bf16 = 4194304 f -> 5873152
constexpr size_t OFF_A2    = 5873152;  // 8192*64 (a3 aliases) -> 6397440
constexpr size_t OFF_A4    = 6397440;  // 8192*128 -> 7446016
constexpr size_t OFF_A4P   = 7446016;  // 8192*256 bf16 = 1048576 f -> 8494592
constexpr size_t OFF_P2    = 8494592;  // 128*64*2 -> 8527360 (reserve)
constexpr size_t OFF_P3    = 8527360;  // -> 8560128
constexpr size_t OFF_P4    = 8560128;  // 128*128*2 -> 8625664 (reserve)
constexpr size_t OFF_P5    = 8625664;  // 128*1024*2 -> 8887808
constexpr size_t OFF_MX5   = 8887808;  // 128*1024 -> 9018880
constexpr size_t OFF_BT2   = 9018880;  // 64*1536 bf16 -> 9068032
constexpr size_t OFF_BT3   = 9068032;  // -> 9117184
constexpr size_t OFF_BT4   = 9117184;  // 128*1536 bf16 -> 9215488
constexpr size_t OFF_BT5   = 9215488;  // 1024*384 bf16 -> 9412096
constexpr size_t OFF_POOL  = 9412096;  // 8*1024 -> 9420288
constexpr size_t OFF_A6    = 9420288;  // 8*512 -> 9424384
constexpr size_t OFF_CP    = 9424384;  // 6*8192*128 = 6291456 -> 15715840 (62.9 MB total)

__device__ __forceinline__ float wredf(float v) {
  #pragma unroll
  for (int o = 32; o > 0; o >>= 1) v += __shfl_xor(v, o, 64);
  return v;
}
__device__ __forceinline__ int wmini(int v) {
  #pragma unroll
  for (int o = 32; o > 0; o >>= 1) v = min(v, __shfl_xor(v, o, 64));
  return v;
}
__device__ __forceinline__ unsigned short f2bf(float f) {   // RNE
  unsigned int u = __float_as_uint(f);
  return (unsigned short)((u + 0x7FFFu + ((u >> 16) & 1u)) >> 16);
}
__device__ __forceinline__ float bf2f(unsigned short h) {
  return __uint_as_float(((unsigned int)h) << 16);
}

// ---------------- KNN + xyz + f0 (blocks 0..2047) | B-split (2048..5119) ----------------
__global__ __launch_bounds__(256) void k_prep(const float* __restrict__ x,
    const float* __restrict__ c1w, int* __restrict__ idxg,
    float* __restrict__ xyz, float* __restrict__ f0,
    const float* __restrict__ mat2, const float* __restrict__ mat3,
    const float* __restrict__ mat4, const float* __restrict__ c5w,
    unsigned short* __restrict__ bt2, unsigned short* __restrict__ bt3,
    unsigned short* __restrict__ bt4, unsigned short* __restrict__ bt5)
{
  int tid = threadIdx.x;
  if (blockIdx.x >= 2048) {           // ---- b-split part ----
    int blk = blockIdx.x - 2048;
    if (blk < 384) {                  // Bt2: 64 x 1536
      int e = blk*256 + tid;
      int o = e / 1536, k2 = e % 1536, p = k2 >> 9, k = k2 & 511;
      float f = mat2[(k & 63)*512 + (k >> 6)*64 + o];
      unsigned short h = f2bf(f);
      bt2[e] = (p < 2) ? h : f2bf(f - bf2f(h));
    } else if (blk < 768) {
      int e = (blk - 384)*256 + tid;
      int o = e / 1536, k2 = e % 1536, p = k2 >> 9, k = k2 & 511;
      float f = mat3[(k & 63)*512 + (k >> 6)*64 + o];
      unsigned short h = f2bf(f);
      bt3[e] = (p < 2) ? h : f2bf(f - bf2f(h));
    } else if (blk < 1536) {          // Bt4: 128 x 1536
      int e = (blk - 768)*256 + tid;
      int o = e / 1536, k2 = e % 1536, p = k2 >> 9, k = k2 & 511;
      float f = mat4[(k & 63)*1024 + (k >> 6)*128 + o];
      unsigned short h = f2bf(f);
      bt4[e] = (p < 2) ? h : f2bf(f - bf2f(h));
    } else {                          // Bt5: 1024 x 384
      int e = (blk - 1536)*256 + tid;
      int o = e / 384, k2 = e % 384, p = k2 >> 7, k = k2 & 127;
      float f = c5w[o*128 + k];
      unsigned short h = f2bf(f);
      bt5[e] = (p < 2) ? h : f2bf(f - bf2f(h));
    }
    return;
  }
  __shared__ float4 pts4[1024];
  int b = blockIdx.x >> 8;
  int wid = tid >> 6, lane = tid & 63;
  for (int i = tid; i < 1024; i += 256) {
    float px = x[(b*3+0)*1024 + i];
    float py = x[(b*3+1)*1024 + i];
    float pz = x[(b*3+2)*1024 + i];
    pts4[i] = make_float4(px, py, pz, px*px + py*py + pz*pz);
  }
  __syncthreads();
  int nq = ((blockIdx.x & 255) << 2) + wid;
  float4 q = pts4[nq];
  int qrow = b*1024 + nq;
  {
    float w0 = c1w[lane*3+0], w1 = c1w[lane*3+1], w2 = c1w[lane*3+2];
    f0[(size_t)qrow*64 + lane] = q.x*w0 + q.y*w1 + q.z*w2;
  }
  unsigned int uk[16];
  #pragma unroll
  for (int i = 0; i < 16; ++i) {
    float4 pm = pts4[i*64 + lane];
    float d = 2.f*(q.x*pm.x + q.y*pm.y + q.z*pm.z) - q.w - pm.w;
    unsigned int bits = __float_as_uint(d);
    uk[i] = bits ^ ((bits & 0x80000000u) ? 0xFFFFFFFFu : 0x80000000u);
  }
  unsigned int lo = 0u, hi = 0xFFFFFFFFu;
  while (lo < hi) {
    unsigned int mid = lo + ((hi - lo) >> 1);
    int cnt = 0;
    #pragma unroll
    for (int i = 0; i < 16; ++i) cnt += (int)__popcll(__ballot(uk[i] > mid));
    if (cnt <= 19) hi = mid; else lo = mid + 1u;
  }
  unsigned int V = lo;
  unsigned int sel = 0; int cg = 0;
  #pragma unroll
  for (int i = 0; i < 16; ++i) {
    bool gt = uk[i] > V;
    if (gt) sel |= (1u << i);
    cg += (int)__popcll(__ballot(gt));
  }
  int r = 20 - cg;            // #ties to take, smallest index first
  unsigned int taken = 0;
  while (r > 0) {
    int jm = 0x7FFFFFFF;
    #pragma unroll
    for (int i = 0; i < 16; ++i)
      if ((uk[i] == V) && !((taken >> i) & 1u) && jm == 0x7FFFFFFF) jm = i*64 + lane;
    int jw = wmini(jm);
    if ((jw & 63) == lane) { int ii = jw >> 6; taken |= (1u << ii); sel |= (1u << ii); }
    --r;
  }
  int cl = __popc(sel);
  int pre = cl;
  #pragma unroll
  for (int o = 1; o < 64; o <<= 1) { int t = __shfl_up(pre, o, 64); if (lane >= o) pre += t; }
  int slot = pre - cl;
  #pragma unroll
  for (int i = 0; i < 16; ++i) {
    if ((sel >> i) & 1u) {
      int j = i*64 + lane;
      idxg[qrow*20 + slot] = b*1024 + j;
      float4 pm = pts4[j];
      float* xr = xyz + (size_t)(qrow*20 + slot)*6;
      xr[0] = pm.x - q.x; xr[1] = pm.y - q.y; xr[2] = pm.z - q.z;
      xr[3] = pm.x; xr[4] = pm.y; xr[5] = pm.z;
      ++slot;
    }
  }
}

// ---------------- stats: xyz moments (0..159) + pts moments (160..163), fence-free ----------------
__global__ __launch_bounds__(256) void k_stats(const float* __restrict__ xyz,
    const float* __restrict__ x, float* __restrict__ hMom, float* __restrict__ pM)
{
  __shared__ float lred[512];
  int tid = threadIdx.x, blk = blockIdx.x;
  int wid = tid >> 6, lane = tid & 63;
  if (blk < 160) {
    float m1[6] = {0,0,0,0,0,0};
    float m2[36];
    #pragma unroll
    for (int i = 0; i < 36; ++i) m2[i] = 0.f;
    for (int it = 0; it < 4; ++it) {
      size_t rr = (size_t)blk*1024 + it*256 + tid;
      const float* xr = xyz + rr*6;
      float v[6];
      #pragma unroll
      for (int d = 0; d < 6; ++d) v[d] = xr[d];
      #pragma unroll
      for (int d = 0; d < 6; ++d) {
        m1[d] += v[d];
        #pragma unroll
        for (int e = 0; e < 6; ++e) m2[d*6+e] += v[d]*v[e];
      }
    }
    #pragma unroll
    for (int i = 0; i < 6; ++i) m1[i] = wredf(m1[i]);
    #pragma unroll
    for (int i = 0; i < 36; ++i) m2[i] = wredf(m2[i]);
    if (lane == 0) {
      #pragma unroll
      for (int i = 0; i < 6; ++i) lred[wid*42 + i] = m1[i];
      #pragma unroll
      for (int i = 0; i < 36; ++i) lred[wid*42 + 6 + i] = m2[i];
    }
    __syncthreads();
    if (tid < 42) hMom[blk*42 + tid] = lred[tid] + lred[42+tid] + lred[84+tid] + lred[126+tid];
  } else {
    int pb = blk - 160;           // 2 batches per block
    float m1[3] = {0,0,0};
    float m2[9] = {0,0,0,0,0,0,0,0,0};
    for (int b2 = 0; b2 < 2; ++b2) {
      int b = pb*2 + b2;
      for (int it = 0; it < 4; ++it) {
        int i = it*256 + tid;
        float p0 = x[(b*3+0)*1024 + i];
        float p1 = x[(b*3+1)*1024 + i];
        float p2 = x[(b*3+2)*1024 + i];
        m1[0]+=p0; m1[1]+=p1; m1[2]+=p2;
        m2[0]+=p0*p0; m2[1]+=p0*p1; m2[2]+=p0*p2;
        m2[3]+=p1*p0; m2[4]+=p1*p1; m2[5]+=p1*p2;
        m2[6]+=p2*p0; m2[7]+=p2*p1; m2[8]+=p2*p2;
      }
    }
    #pragma unroll
    for (int i = 0; i < 3; ++i) m1[i] = wredf(m1[i]);
    #pragma unroll
    for (int i = 0; i < 9; ++i) m2[i] = wredf(m2[i]);
    if (lane == 0) {
      #pragma unroll
      for (int i = 0; i < 3; ++i) lred[wid*12 + i] = m1[i];
      #pragma unroll
      for (int i = 0; i < 9; ++i) lred[wid*12 + 3 + i] = m2[i];
    }
    __syncthreads();
    if (tid < 12) pM[pb*12 + tid] = lred[tid] + lred[12+tid] + lred[24+tid] + lred[36+tid];
  }
}

// ---------------- coefA: moments -> scorenet coefs (3 stages) + bn1 coefs (1 block) ----------------
__global__ __launch_bounds__(256) void k_coefA(
    const float* __restrict__ hMom, const float* __restrict__ pM,
    const float* __restrict__ c1w, const float* __restrict__ bn1g, const float* __restrict__ bn1b,
    const float* __restrict__ w1a, const float* __restrict__ w1b, const float* __restrict__ w1c,
    const float* __restrict__ sga, const float* __restrict__ sgb, const float* __restrict__ sgc,
    const float* __restrict__ sba, const float* __restrict__ sbb, const float* __restrict__ sbc,
    float* __restrict__ scoef, float* __restrict__ pcoef)
{
  __shared__ float lred[192];
  __shared__ float momS[42], pmS[12];
  int tid = threadIdx.x;
  if (tid < 168) {
    int ch = tid % 42, seg = tid / 42;
    float s = 0.f;
    #pragma unroll 8
    for (int pb = seg*40; pb < seg*40 + 40; ++pb) s += hMom[pb*42 + ch];
    lred[seg*42 + ch] = s;
  } else if (tid >= 192 && tid < 204) {
    int i = tid - 192;
    pmS[i] = pM[i] + pM[12+i] + pM[24+i] + pM[36+i];
  }
  __syncthreads();
  if (tid < 42) momS[tid] = (lred[tid] + lred[42+tid] + lred[84+tid] + lred[126+tid]) / (float)KPn;
  __syncthreads();
  if (tid < 48) {
    int st = tid >> 4, c = tid & 15;
    const float* w1 = (st == 0) ? w1a : (st == 1) ? w1b : w1c;
    const float* sg = (st == 0) ? sga : (st == 1) ? sgb : sgc;
    const float* sb = (st == 0) ? sba : (st == 1) ? sbb : sbc;
    float wv[6];
    #pragma unroll
    for (int d = 0; d < 6; ++d) wv[d] = w1[c*6 + d];
    float mu = 0.f, E2 = 0.f;
    #pragma unroll
    for (int d = 0; d < 6; ++d) mu += wv[d]*momS[d];
    #pragma unroll
    for (int d = 0; d < 6; ++d) {
      float qd = 0.f;
      #pragma unroll
      for (int e = 0; e < 6; ++e) qd += momS[6 + d*6 + e]*wv[e];
      E2 += wv[d]*qd;
    }
    float var = E2 - mu*mu;
    float rst = rsqrtf(var + EPS_);
    float g = sg[c];
    scoef[st*32 + c] = g*rst;
    scoef[st*32 + 16 + c] = sb[c] - mu*g*rst;
  } else if (tid >= 64 && tid < 128) {
    int c = tid - 64;
    float wv0 = c1w[c*3+0], wv1 = c1w[c*3+1], wv2 = c1w[c*3+2];
    float mu = (wv0*pmS[0] + wv1*pmS[1] + wv2*pmS[2]) / 8192.f;
    float E2 = (wv0*(pmS[3]*wv0 + pmS[4]*wv1 + pmS[5]*wv2)
              + wv1*(pmS[6]*wv0 + pmS[7]*wv1 + pmS[8]*wv2)
              + wv2*(pmS[9]*wv0 + pmS[10]*wv1 + pmS[11]*wv2)) / 8192.f;
    float var = E2 - mu*mu;
    float rst = rsqrtf(var + EPS_);
    float g = bn1g[c];
    pcoef[c] = g*rst;
    pcoef[64 + c] = bn1b[c] - mu*g*rst;
  }
}

// ---------------- W-build: per-wave scorenet + gather ----------------
__global__ __launch_bounds__(256) void k_wbuild(
    const float* __restrict__ xyz, const int* __restrict__ idxg,
    const float* __restrict__ aprev, const float* __restrict__ scoef,
    const float* __restrict__ pcoef,
    const float* __restrict__ w1, const float* __restrict__ w2, const float* __restrict__ b2,
    unsigned short* __restrict__ Wo)
{
  __shared__ float scoreS[4][20][8];
  int tid = threadIdx.x;
  int wid = tid >> 6, lane = tid & 63;
  int p = blockIdx.x*4 + wid;
  if (lane < 20) {
    const float* xr = xyz + (size_t)(p*20 + lane)*6;
    float v0=xr[0],v1=xr[1],v2=xr[2],v3=xr[3],v4=xr[4],v5=xr[5];
    float hb[16];
    #pragma unroll
    for (int c = 0; c < 16; ++c) {
      float h = v0*w1[c*6+0]+v1*w1[c*6+1]+v2*w1[c*6+2]+v3*w1[c*6+3]+v4*w1[c*6+4]+v5*w1[c*6+5];
      hb[c] = fmaxf(0.f, h*scoef[c] + scoef[16+c]);
    }
    float lg[8]; float mx = -3.4e38f;
    #pragma unroll
    for (int m = 0; m < 8; ++m) {
      float s = b2[m];
      #pragma unroll
      for (int c = 0; c < 16; ++c) s += hb[c]*w2[m*16+c];
      lg[m] = s; mx = fmaxf(mx, s);
    }
    float den = 0.f;
    #pragma unroll
    for (int m = 0; m < 8; ++m) { lg[m] = expf(lg[m]-mx); den += lg[m]; }
    #pragma unroll
    for (int m = 0; m < 8; ++m) scoreS[wid][lane][m] = lg[m]/den;
  }
  __syncthreads();
  float ps = pcoef[lane], ph = pcoef[64 + lane];
  float acc[8];
  #pragma unroll
  for (int m = 0; m < 8; ++m) acc[m] = 0.f;
  const int* ip = idxg + p*20;
  #pragma unroll
  for (int k = 0; k < 20; ++k) {
    int j = ip[k];
    float v = aprev[(size_t)j*64 + lane];
    v = fmaxf(0.f, v*ps + ph);
    #pragma unroll
    for (int m = 0; m < 8; ++m) acc[m] += scoreS[wid][k][m]*v;
  }
  #pragma unroll
  for (int m = 0; m < 8; ++m) {
    float v = acc[m];
    unsigned short h = f2bf(v);
    unsigned short l = f2bf(v - bf2f(h));
    Wo[(size_t)p*1024 + m*64 + lane] = h;
    Wo[(size_t)p*1024 + 512 + m*64 + lane] = l;
  }
}

// ---------------- K-split MFMA gemm: partial 64x64 tile over 256 K'-cols (fence-free) ----------------
template<int CO>
__global__ __launch_bounds__(256) void k_mg(
    const unsigned short* __restrict__ A, const unsigned short* __restrict__ Bt,
    float* __restrict__ Cp)
{
  __shared__ __align__(16) unsigned short As[4096];
  __shared__ __align__(16) unsigned short Bs[4096];
  int tid = threadIdx.x;
  int rb = blockIdx.x, gy = blockIdx.y, ck = blockIdx.z;
  int w = tid >> 6, lane = tid & 63;
  int wr = w & 1, wc = w >> 1;
  int r = tid >> 2, q = tid & 3;
  int abase = ((ck >> 1) == 1 ? 512 : 0) + (ck & 1)*256;
  int bbase = ck*256;
  f32x4 acc00 = {0,0,0,0}, acc01 = {0,0,0,0}, acc10 = {0,0,0,0}, acc11 = {0,0,0,0};
  const size_t arow = (size_t)(rb*64 + r)*1024 + abase + q*16;
  const size_t brow = (size_t)(gy*64 + r)*1536 + bbase + q*16;
  float4 ra0, ra1, rbv0, rbv1;
  #define MG_LOAD(IT) { \
    const float4* ap_ = (const float4*)(A + arow + (IT)*64); ra0 = ap_[0]; ra1 = ap_[1]; \
    const float4* bp_ = (const float4*)(Bt + brow + (IT)*64); rbv0 = bp_[0]; rbv1 = bp_[1]; }
  MG_LOAD(0);
  int wbase = r*128 + q*32, sw = (r & 7) << 4;
  for (int it = 0; it < 4; ++it) {
    __syncthreads();
    *(float4*)((char*)As + ((wbase)      ^ sw)) = ra0;
    *(float4*)((char*)As + ((wbase + 16) ^ sw)) = ra1;
    *(float4*)((char*)Bs + ((wbase)      ^ sw)) = rbv0;
    *(float4*)((char*)Bs + ((wbase + 16) ^ sw)) = rbv1;
    __syncthreads();
    if (it < 3) MG_LOAD(it + 1);
    #pragma unroll
    for (int ks = 0; ks < 2; ++ks) {
      int kb2 = (ks*32 + ((lane >> 4) << 3))*2;
      int ar0 = wr*32 + (lane & 15), ar1 = ar0 + 16;
      int bc0 = wc*32 + (lane & 15), bc1 = bc0 + 16;
      s8v a0 = *(const s8v*)((const char*)As + ((ar0*128 + kb2) ^ ((ar0 & 7) << 4)));
      s8v a1 = *(const s8v*)((const char*)As + ((ar1*128 + kb2) ^ ((ar1 & 7) << 4)));
      s8v b0 = *(const s8v*)((const char*)Bs + ((bc0*128 + kb2) ^ ((bc0 & 7) << 4)));
      s8v b1 = *(const s8v*)((const char*)Bs + ((bc1*128 + kb2) ^ ((bc1 & 7) << 4)));
      acc00 = MFMA16(a0, b0, acc00, 0, 0, 0);
      acc01 = MFMA16(a0, b1, acc01, 0, 0, 0);
      acc10 = MFMA16(a1, b0, acc10, 0, 0, 0);
      acc11 = MFMA16(a1, b1, acc11, 0, 0, 0);
    }
  }
  #undef MG_LOAD
  int rr = (lane >> 4)*4, cc = lane & 15;
  float* Co = Cp + (size_t)ck*((size_t)8192*CO);
  size_t rbase = (size_t)rb*64 + wr*32 + rr;
  int cbase = gy*64 + wc*32 + cc;
  #pragma unroll
  for (int u = 0; u < 4; ++u) {
    Co[(rbase + u)*CO + cbase]           = acc00[u];
    Co[(rbase + u)*CO + cbase + 16]      = acc01[u];
    Co[(rbase + 16 + u)*CO + cbase]      = acc10[u];
    Co[(rbase + 16 + u)*CO + cbase + 16] = acc11[u];
  }
}

// ---------------- reduce 6 partials -> C + col partials (fence-free, 128 blocks) ----------------
template<int CO, int NCH>
__global__ __launch_bounds__(256) void k_red(
    const float* __restrict__ Cp, float* __restrict__ C, float* __restrict__ P)
{
  static_assert(NCH == 6, "hardwired 6-chunk sum");
  __shared__ float red[256][8];
  constexpr int F = (64*CO)/1024;          // 4 (CO=64) or 8 (CO=128)
  constexpr size_t SZ = (size_t)8192*CO;
  int tid = threadIdx.x, bid = blockIdx.x;  // 128 blocks, 64 rows each
  float cs[4] = {0,0,0,0}, cq[4] = {0,0,0,0};
  #pragma unroll
  for (int f = 0; f < F; ++f) {
    size_t idx = (size_t)bid*(64*CO) + f*1024 + tid*4;
    float4 u0 = *(const float4*)(Cp + idx);
    float4 u1 = *(const float4*)(Cp + SZ + idx);
    float4 u2 = *(const float4*)(Cp + 2*SZ + idx);
    float4 u3 = *(const float4*)(Cp + 3*SZ + idx);
    float4 u4 = *(const float4*)(Cp + 4*SZ + idx);
    float4 u5 = *(const float4*)(Cp + 5*SZ + idx);
    float4 v;
    v.x = ((u0.x + u1.x) + (u2.x + u3.x)) + (u4.x + u5.x);
    v.y = ((u0.y + u1.y) + (u2.y + u3.y)) + (u4.y + u5.y);
    v.z = ((u0.z + u1.z) + (u2.z + u3.z)) + (u4.z + u5.z);
    v.w = ((u0.w + u1.w) + (u2.w + u3.w)) + (u4.w + u5.w);
    *(float4*)(C + idx) = v;
    cs[0] += v.x; cq[0] += v.x*v.x;
    cs[1] += v.y; cq[1] += v.y*v.y;
    cs[2] += v.z; cq[2] += v.z*v.z;
    cs[3] += v.w; cq[3] += v.w*v.w;
  }
  #pragma unroll
  for (int u = 0; u < 4; ++u) { red[tid][2*u] = cs[u]; red[tid][2*u+1] = cq[u]; }
  __syncthreads();
  if (tid < CO) {
    int c = tid, base = c >> 2, slot = c & 3;
    float s = 0.f, qq = 0.f;
    #pragma unroll
    for (int j = 0; j < 256/(CO/4); ++j) {
      int t = base + (CO/4)*j;
      s += red[t][2*slot]; qq += red[t][2*slot+1];
    }
    P[((size_t)bid*CO + c)*2]     = s;
    P[((size_t)bid*CO + c)*2 + 1] = qq;
  }
}

// ---------------- coefB: P (128 rows) -> BN scale/shift (1 block) ----------------
template<int CO>
__global__ __launch_bounds__(256) void k_coefB(const float* __restrict__ P,
    const float* __restrict__ g, const float* __restrict__ b, float* __restrict__ coefOut)
{
  __shared__ float rs[256], rq[256];
  constexpr int NSEG = 256/CO;      // 4 (CO=64) or 2 (CO=128)
  constexpr int RPS  = 128/NSEG;    // 32 or 64
  int tid = threadIdx.x;
  int c = tid % CO, seg = tid / CO;
  float s = 0.f, qq = 0.f;
  #pragma unroll 8
  for (int j = 0; j < RPS; ++j) {
    int p2 = seg*RPS + j;
    s  += P[((size_t)p2*CO + c)*2];
    qq += P[((size_t)p2*CO + c)*2 + 1];
  }
  rs[seg*CO + c] = s; rq[seg*CO + c] = qq;
  __syncthreads();
  if (tid < CO) {
    float s2 = 0.f, q2 = 0.f;
    #pragma unroll
    for (int gs = 0; gs < NSEG; ++gs) { s2 += rs[gs*CO + tid]; q2 += rq[gs*CO + tid]; }
    float mu = s2/8192.f, var = q2/8192.f - mu*mu;
    float rst = rsqrtf(var + EPS_);
    coefOut[tid] = g[tid]*rst;
    coefOut[CO + tid] = b[tid] - mu*g[tid]*rst;
  }
}

// ---------------- pack: a4p = hi/lo bf16 of relu(bn4(a4)) ----------------
__global__ __launch_bounds__(256) void k_pack(const float* __restrict__ a4,
    const float* __restrict__ bnc, unsigned short* __restrict__ a4p)
{
  int gid = blockIdx.x*256 + threadIdx.x;   // 262144
  int row = gid >> 5, c4 = (gid & 31)*4;
  float4 v = *(const float4*)(a4 + (size_t)row*128 + c4);
  float y0 = fmaxf(0.f, v.x*bnc[c4+0] + bnc[128+c4+0]);
  float y1 = fmaxf(0.f, v.y*bnc[c4+1] + bnc[128+c4+1]);
  float y2 = fmaxf(0.f, v.z*bnc[c4+2] + bnc[128+c4+2]);
  float y3 = fmaxf(0.f, v.w*bnc[c4+3] + bnc[128+c4+3]);
  ushort4 hi = make_ushort4(f2bf(y0), f2bf(y1), f2bf(y2), f2bf(y3));
  ushort4 lov = make_ushort4(f2bf(y0 - bf2f(hi.x)), f2bf(y1 - bf2f(hi.y)),
                             f2bf(y2 - bf2f(hi.z)), f2bf(y3 - bf2f(hi.w)));
  *(ushort4*)(a4p + (size_t)row*256 + c4) = hi;
  *(ushort4*)(a4p + (size_t)row*256 + 128 + c4) = lov;
}

// ---------------- MFMA gemm5: a4p(bf16 hi/lo) x bt5 -> partials + max ----------------
__global__ __launch_bounds__(256) void k_g5(const unsigned short* __restrict__ A4P,
    const unsigned short* __restrict__ Bt,
    float* __restrict__ outPart, float* __restrict__ outMax)
{
  __shared__ __align__(16) unsigned short As[4096];
  __shared__ __align__(16) unsigned short Bs[4096];
  __shared__ float colS[4][64], colQ[4][64], colM[4][64];
  int tid = threadIdx.x;
  int rb = blockIdx.x, gy = blockIdx.y;
  int w = tid >> 6, lane = tid & 63;
  int wr = w & 1, wc = w >> 1;
  int r = tid >> 2, q = tid & 3;
  f32x4 acc00={0,0,0,0}, acc01={0,0,0,0}, acc10={0,0,0,0}, acc11={0,0,0,0};
  uint4 ua0, ua1, ub0, ub1;
  #define G5_LOAD(IT) { int p_ = (IT) >> 1; int acol = (p_ == 1 ? 128 : 0) + (((IT) & 1) << 6); \
    const uint4* ap_ = (const uint4*)(A4P + (size_t)(rb*64 + r)*256 + acol + q*16); \
    ua0 = ap_[0]; ua1 = ap_[1]; \
    const uint4* bp_ = (const uint4*)(Bt + (size_t)(gy*64 + r)*384 + (size_t)(IT)*64 + q*16); \
    ub0 = bp_[0]; ub1 = bp_[1]; }
  G5_LOAD(0);
  int wbase = r*128 + q*32, sw = (r & 7) << 4;
  for (int it = 0; it < 6; ++it) {
    __syncthreads();
    *(uint4*)((char*)As + ((wbase)      ^ sw)) = ua0;
    *(uint4*)((char*)As + ((wbase + 16) ^ sw)) = ua1;
    *(uint4*)((char*)Bs + ((wbase)      ^ sw)) = ub0;
    *(uint4*)((char*)Bs + ((wbase + 16) ^ sw)) = ub1;
    __syncthreads();
    if (it < 5) G5_LOAD(it + 1);
    #pragma unroll
    for (int ks = 0; ks < 2; ++ks) {
      int kb2 = (ks*32 + ((lane >> 4) << 3))*2;
      int ar0 = wr*32 + (lane & 15), ar1 = ar0 + 16;
      int bc0 = wc*32 + (lane & 15), bc1 = bc0 + 16;
      s8v a0 = *(const s8v*)((const char*)As + ((ar0*128 + kb2) ^ ((ar0 & 7) << 4)));
      s8v a1 = *(const s8v*)((const char*)As + ((ar1*128 + kb2) ^ ((ar1 & 7) << 4)));
      s8v b0 = *(const s8v*)((const char*)Bs + ((bc0*128 + kb2) ^ ((bc0 & 7) << 4)));
      s8v b1 = *(const s8v*)((const char*)Bs + ((bc1*128 + kb2) ^ ((bc1 & 7) << 4)));
      acc00 = MFMA16(a0, b0, acc00, 0, 0, 0);
      acc01 = MFMA16(a0, b1, acc01, 0, 0, 0);
      acc10 = MFMA16(a1, b0, acc10, 0, 0, 0);
      acc11 = MFMA16(a1, b1, acc11, 0, 0, 0);
    }
  }
  #undef G5_LOAD
  int cc = lane & 15;
  {
    float s0=0.f,q0=0.f,m0=-3.4e38f, s1=0.f,q1=0.f,m1=-3.4e38f;
    #pragma unroll
    for (int u = 0; u < 4; ++u) {
      s0 += acc00[u] + acc10[u]; q0 += acc00[u]*acc00[u] + acc10[u]*acc10[u];
      m0 = fmaxf(m0, fmaxf(acc00[u], acc10[u]));
      s1 += acc01[u] + acc11[u]; q1 += acc01[u]*acc01[u] + acc11[u]*acc11[u];
      m1 = fmaxf(m1, fmaxf(acc01[u], acc11[u]));
    }
    s0 += __shfl_xor(s0,16,64); s0 += __shfl_xor(s0,32,64);
    q0 += __shfl_xor(q0,16,64); q0 += __shfl_xor(q0,32,64);
    m0 = fmaxf(m0, __shfl_xor(m0,16,64)); m0 = fmaxf(m0, __shfl_xor(m0,32,64));
    s1 += __shfl_xor(s1,16,64); s1 += __shfl_xor(s1,32,64);
    q1 += __shfl_xor(q1,16,64); q1 += __shfl_xor(q1,32,64);
    m1 = fmaxf(m1, __shfl_xor(m1,16,64)); m1 = fmaxf(m1, __shfl_xor(m1,32,64));
    if (lane < 16) {
      colS[w][wc*32 + cc] = s0;      colQ[w][wc*32 + cc] = q0;      colM[w][wc*32 + cc] = m0;
      colS[w][wc*32 + 16 + cc] = s1; colQ[w][wc*32 + 16 + cc] = q1; colM[w][wc*32 + 16 + cc] = m1;
    }
  }
  __syncthreads();
  if (tid < 64) {
    int c = tid, wc2 = c >> 5;
    float s = colS[2*wc2][c] + colS[2*wc2+1][c];
    float qq = colQ[2*wc2][c] + colQ[2*wc2+1][c];
    float m = fmaxf(colM[2*wc2][c], colM[2*wc2+1][c]);
    outPart[((size_t)rb*1024 + gy*64 + c)*2]     = s;
    outPart[((size_t)rb*1024 + gy*64 + c)*2 + 1] = qq;
    outMax[(size_t)rb*1024 + gy*64 + c] = m;
  }
}

// ---------------- bn5 + relu + maxpool (128 blocks) ----------------
__global__ __launch_bounds__(256) void k_pool(const float* __restrict__ p5, const float* __restrict__ mx5,
    const float* __restrict__ g5, const float* __restrict__ b5, float* __restrict__ pool)
{
  __shared__ float red[4][64][2];
  int tid = threadIdx.x, bid = blockIdx.x;
  int b = bid >> 4, cg = bid & 15;
  int c4 = tid & 63, seg = tid >> 6;
  int ch = cg*64 + c4;
  float s = 0.f, qq = 0.f;
  for (int rb = seg*32; rb < seg*32 + 32; ++rb) {
    s  += p5[((size_t)rb*1024 + ch)*2];
    qq += p5[((size_t)rb*1024 + ch)*2 + 1];
  }
  red[seg][c4][0] = s; red[seg][c4][1] = qq;
  __syncthreads();
  if (seg == 0) {
    s  = red[0][c4][0] + red[1][c4][0] + red[2][c4][0] + red[3][c4][0];
    qq = red[0][c4][1] + red[1][c4][1] + red[2][c4][1] + red[3][c4][1];
    float mu = s / 8192.f;
    float var = qq / 8192.f - mu*mu;
    float rst = rsqrtf(var + EPS_);
    float mx = -3.4e38f;
    #pragma unroll
    for (int t = 0; t < 16; ++t) mx = fmaxf(mx, mx5[(size_t)(b*16 + t)*1024 + ch]);
    pool[b*1024 + ch] = fmaxf(0.f, g5[ch]*(mx - mu)*rst + b5[ch]);
  }
}

// ---------------- lin1: wave per output ----------------
__global__ __launch_bounds__(256) void k_lin1(const float* __restrict__ pool,
    const float* __restrict__ w, float* __restrict__ a6)
{
  int wid = threadIdx.x >> 6, lane = threadIdx.x & 63;
  int o = blockIdx.x*4 + wid;
  int r = o >> 9, c = o & 511;
  const float4* pr = (const float4*)(pool + r*1024);
  const float4* wr = (const float4*)(w + (size_t)c*1024);
  float s = 0.f;
  #pragma unroll
  for (int t = 0; t < 4; ++t) {
    float4 a = pr[lane + 64*t], b = wr[lane + 64*t];
    s += a.x*b.x + a.y*b.y + a.z*b.z + a.w*b.w;
  }
  s = wredf(s);
  if (lane == 0) a6[o] = s;
}

// ---------------- head: wave per output ----------------
__global__ __launch_bounds__(256) void k_head(const float* __restrict__ a6,
    const float* __restrict__ g6, const float* __restrict__ b6,
    const float* __restrict__ w2, const float* __restrict__ bb,
    float* __restrict__ out)
{
  int wid = threadIdx.x >> 6, lane = threadIdx.x & 63;
  int o = blockIdx.x*4 + wid;
  int r = o / 40, c2 = o % 40;
  float s = 0.f;
  #pragma unroll
  for (int j = 0; j < 8; ++j) {
    int c = lane + 64*j;
    float sum = 0.f, vr = 0.f;
    float v[8];
    #pragma unroll
    for (int rr = 0; rr < 8; ++rr) { v[rr] = a6[rr*512 + c]; sum += v[rr]; }
    #pragma unroll
    for (int rr = 0; rr < 8; ++rr) vr = (rr == r) ? v[rr] : vr;
    float mu = sum / 8.f;
    float qq = 0.f;
    #pragma unroll
    for (int rr = 0; rr < 8; ++rr) { float d = v[rr] - mu; qq += d*d; }
    float rst = rsqrtf(qq / 8.f + EPS_);
    float f6r = fmaxf(0.f, (vr - mu)*g6[c]*rst + b6[c]);
    s += f6r * w2[c2*512 + c];
  }
  s = wredf(s);
  if (lane == 0) out[o] = s + bb[c2];
}

extern "C" void kernel_launch(void* const* d_in, const int* in_sizes, int n_in,
                              void* d_out, int out_size, void* d_ws, size_t ws_size,
                              hipStream_t stream) {
  (void)in_sizes; (void)n_in; (void)out_size; (void)ws_size;
  const float* x     = (const float*)d_in[0];
  const float* c1w   = (const float*)d_in[1];
  const float* bn1g  = (const float*)d_in[2];
  const float* bn1b  = (const float*)d_in[3];
  const float* mat2  = (const float*)d_in[4];
  const float* mat3  = (const float*)d_in[5];
  const float* mat4  = (const float*)d_in[6];
  const float* sn2w1 = (const float*)d_in[7];
  const float* sn2g  = (const float*)d_in[8];
  const float* sn2b  = (const float*)d_in[9];
  const float* sn2w2 = (const float*)d_in[10];
  const float* sn2b2 = (const float*)d_in[11];
  const float* sn3w1 = (const float*)d_in[12];
  const float* sn3g  = (const float*)d_in[13];
  const float* sn3b  = (const float*)d_in[14];
  const float* sn3w2 = (const float*)d_in[15];
  const float* sn3b2 = (const float*)d_in[16];
  const float* sn4w1 = (const float*)d_in[17];
  const float* sn4g  = (const float*)d_in[18];
  const float* sn4b  = (const float*)d_in[19];
  const float* sn4w2 = (const float*)d_in[20];
  const float* sn4b2 = (const float*)d_in[21];
  const float* bn2g  = (const float*)d_in[22];
  const float* bn2b  = (const float*)d_in[23];
  const float* bn3g  = (const float*)d_in[24];
  const float* bn3b  = (const float*)d_in[25];
  const float* bn4g  = (const float*)d_in[26];
  const float* bn4b  = (const float*)d_in[27];
  const float* c5w   = (const float*)d_in[28];
  const float* bn5g  = (const float*)d_in[29];
  const float* bn5b  = (const float*)d_in[30];
  const float* l1w   = (const float*)d_in[31];
  const float* bn6g  = (const float*)d_in[32];
  const float* bn6b  = (const float*)d_in[33];
  const float* l2w   = (const float*)d_in[34];
  const float* l2b   = (const float*)d_in[35];
  float* ws   = (float*)d_ws;
  float* f0    = ws + OFF_F0;
  int*   idxg  = (int*)(ws + OFF_IDX);
  float* xyz   = ws + OFF_XYZ;
  float* hMom  = ws + OFF_HM;
  float* pM    = ws + OFF_PM;
  float* scoef = ws + OFF_SCOEF;
  float* pcoef = ws + OFF_PCOEF;
  float* bn4c  = ws + OFF_BN4C;
  unsigned short* W2  = (unsigned short*)(ws + OFF_W2);
  float* a2    = ws + OFF_A2;          // a3 aliases (lifetimes disjoint)
  float* a4    = ws + OFF_A4;
  unsigned short* a4p = (unsigned short*)(ws + OFF_A4P);
  float* p2    = ws + OFF_P2;
  float* p3    = ws + OFF_P3;
  float* p4    = ws + OFF_P4;
  float* p5    = ws + OFF_P5;
  float* mx5   = ws + OFF_MX5;
  unsigned short* bt2 = (unsigned short*)(ws + OFF_BT2);
  unsigned short* bt3 = (unsigned short*)(ws + OFF_BT3);
  unsigned short* bt4 = (unsigned short*)(ws + OFF_BT4);
  unsigned short* bt5 = (unsigned short*)(ws + OFF_BT5);
  float* pool  = ws + OFF_POOL;
  float* a6    = ws + OFF_A6;
  float* CP    = ws + OFF_CP;
  float* out   = (float*)d_out;

  k_prep<<<5120, 256, 0, stream>>>(x, c1w, idxg, xyz, f0,
      mat2, mat3, mat4, c5w, bt2, bt3, bt4, bt5);
  k_stats<<<164, 256, 0, stream>>>(xyz, x, hMom, pM);
  k_coefA<<<1, 256, 0, stream>>>(hMom, pM, c1w, bn1g, bn1b,
      sn2w1, sn3w1, sn4w1, sn2g, sn3g, sn4g, sn2b, sn3b, sn4b,
      scoef, pcoef);

  k_wbuild<<<2048, 256, 0, stream>>>(xyz, idxg, f0, scoef + 0, pcoef + 0,
      sn2w1, sn2w2, sn2b2, W2);
  k_mg<64><<<dim3(128, 1, 6), 256, 0, stream>>>(W2, bt2, CP);
  k_red<64, 6><<<128, 256, 0, stream>>>(CP, a2, p2);
  k_coefB<64><<<1, 256, 0, stream>>>(p2, bn2g, bn2b, pcoef + 128);

  k_wbuild<<<2048, 256, 0, stream>>>(xyz, idxg, a2, scoef + 32, pcoef + 128,
      sn3w1, sn3w2, sn3b2, W2);
  k_mg<64><<<dim3(128, 1, 6), 256, 0, stream>>>(W2, bt3, CP);
  k_red<64, 6><<<128, 256, 0, stream>>>(CP, a2 /*a3*/, p3);
  k_coefB<64><<<1, 256, 0, stream>>>(p3, bn3g, bn3b, pcoef + 256);

  k_wbuild<<<2048, 256, 0, stream>>>(xyz, idxg, a2 /*a3*/, scoef + 64, pcoef + 256,
      sn4w1, sn4w2, sn4b2, W2);
  k_mg<128><<<dim3(128, 2, 6), 256, 0, stream>>>(W2, bt4, CP);
  k_red<128, 6><<<128, 256, 0, stream>>>(CP, a4, p4);
  k_coefB<128><<<1, 256, 0, stream>>>(p4, bn4g, bn4b, bn4c);

  k_pack<<<1024, 256, 0, stream>>>(a4, bn4c, a4p);
  k_g5<<<dim3(128, 16), 256, 0, stream>>>(a4p, bt5, p5, mx5);

  k_pool<<<128, 256, 0, stream>>>(p5, mx5, bn5g, bn5b, pool);
  k_lin1<<<1024, 256, 0, stream>>>(pool, l1w, a6);
  k_head<<<80, 256, 0, stream>>>(a6, bn6g, bn6b, l2w, l2b, out);
}